// Round 19
// baseline (170.116 us; speedup 1.0000x reference)
//
#include <hip/hip_runtime.h>
#include <math.h>

#define LSEQ 2304
#define LC 32
#define NCH 72

typedef unsigned short u16;
typedef unsigned int u32;
typedef __attribute__((ext_vector_type(8))) short bf16x8;
typedef __attribute__((ext_vector_type(4))) float f32x4;

__device__ __forceinline__ float sigmoidf_(float v){ return 1.f/(1.f+__expf(-v)); }
__device__ __forceinline__ u16 f2b(float f){
  union{float f; u32 u;} v; v.f = f;
  u32 r = v.u + 0x7fffu + ((v.u >> 16) & 1u);
  return (u16)(r >> 16);
}
__device__ __forceinline__ float b2f(u16 h){
  union{u32 u; float f;} v; v.u = ((u32)h) << 16; return v.f;
}
__device__ __forceinline__ u16 f2h(float f){
  _Float16 h = (_Float16)f;
  union{_Float16 h; u16 u;} v; v.h = h; return v.u;
}
__device__ __forceinline__ float h2f(u16 u){
  union{u16 u; _Float16 h;} v; v.u = u; return (float)v.h;
}
__device__ __forceinline__ uint2 pack4(float a, float b, float c, float d){
  uint2 o;
  o.x = (u32)f2b(a) | ((u32)f2b(b) << 16);
  o.y = (u32)f2b(c) | ((u32)f2b(d) << 16);
  return o;
}
__device__ __forceinline__ float softplus_(float v){
  return fmaxf(v, 0.f) + __logf(1.f + __expf(-fabsf(v)));
}

// ---------------- prep (g + invg + LayerNorm merged): fold LN into Win, Wcomb, A2, Wout bf16, A-check ----------------
__global__ __launch_bounds__(256) void prep_fold(const float* __restrict__ Win, const float* __restrict__ ln_g,
                          const float* __restrict__ ln_b, const float* __restrict__ A_log,
                          const float* __restrict__ Wout, const float* __restrict__ Wx,
                          const float* __restrict__ Wdt, const float* __restrict__ bdt,
                          const float* __restrict__ x,
                          u16* __restrict__ WinMF, float* __restrict__ b2,
                          float* __restrict__ Aneg2, u16* __restrict__ WoutMF,
                          u16* __restrict__ Wcomb, float* __restrict__ bcomb,
                          int* __restrict__ g, int* __restrict__ invg, int* __restrict__ flag,
                          u16* __restrict__ n){
  __shared__ float red[512];
  if (blockIdx.x >= 768){
    int tid = threadIdx.x;
    int s = tid & 63, q = tid >> 6;
    int T = (blockIdx.x - 768) * 64 + s;
    int b = T / 2304, p = T % 2304;
    const float* xp = x + (size_t)b * 96 * 2304 + p;
    float vals[24];
    float sum = 0.f, ss = 0.f;
    #pragma unroll
    for (int k = 0; k < 24; ++k){
      float v = xp[(size_t)(q*24 + k) * 2304];
      vals[k] = v; sum += v; ss += v*v;
    }
    red[q*64 + s] = sum;
    red[256 + q*64 + s] = ss;
    __syncthreads();
    float S = red[s] + red[64+s] + red[128+s] + red[192+s];
    float Q = red[256+s] + red[320+s] + red[384+s] + red[448+s];
    float mu = S * (1.f/96.f);
    float var = Q * (1.f/96.f) - mu*mu;
    float rs = rsqrtf(var + 1e-5f);
    u32 w[12];
    #pragma unroll
    for (int k = 0; k < 12; ++k){
      float v0 = (vals[2*k]   - mu) * rs;
      float v1 = (vals[2*k+1] - mu) * rs;
      w[k] = (u32)f2b(v0) | ((u32)f2b(v1) << 16);
    }
    uint4* np_ = (uint4*)(n + (size_t)T * 96 + q*24);
    np_[0] = make_uint4(w[0], w[1], w[2],  w[3]);
    np_[1] = make_uint4(w[4], w[5], w[6],  w[7]);
    np_[2] = make_uint4(w[8], w[9], w[10], w[11]);
    return;
  }
  int i = blockIdx.x * 256 + threadIdx.x;
  if (i < LSEQ){
    int l = i;
    g[l] = l;                                   // row
    g[LSEQ + l] = (l % 48) * 48 + l / 48;       // col
    invg[l] = l;
    invg[LSEQ + l] = (l % 48) * 48 + l / 48;    // col is self-inverse
    int p = i;                                  // diag (scatter) + anti (flip of diag)
    int ii = p / 48, jj = p % 48, dd = jj - ii;
    int off = (dd <= 0) ? (47 + dd) * (48 + dd) / 2
                        : 1176 + 48 * (dd - 1) - dd * (dd - 1) / 2;
    int l2 = off + min(ii, jj);
    g[2 * LSEQ + l2] = p;
    g[3 * LSEQ + l2] = ii * 48 + 47 - jj;
    invg[2 * LSEQ + p] = l2;
    invg[3 * LSEQ + ii * 48 + 47 - jj] = l2;
  }
  if (i < 4*192*16){
    float a = -expf(A_log[i]);
    Aneg2[i] = a * 1.44269504f;   // -exp(A_log)*log2(e)
    int s = i & 15;
    float a0 = -expf(A_log[i - s]);
    if (fabsf(a - (float)(s + 1) * a0) > 1e-5f * fabsf(a) + 1e-30f)
      atomicOr(flag, 1);
  }
  if (i < 4*384*96){
    int d = i / 36864, r = i % 36864, c = r % 96;
    WinMF[i] = f2b(Win[i] * ln_g[d*96 + c]);
  }
  if (i < 4*96*192) WoutMF[i] = f2b(Wout[i]);
  if (i < 4*224*192){
    int d = i / 43008, r = i % 43008, e = r / 192, c = r % 192;
    float w;
    if (e < 192){
      const float* wdt = &Wdt[(size_t)(d*192 + e) * 6];
      w = 0.f;
      #pragma unroll
      for (int r6 = 0; r6 < 6; ++r6) w += wdt[r6] * Wx[(size_t)(d*38 + r6) * 192 + c];
    } else if (e < 208){
      w = Wx[(size_t)(d*38 + 6 + (e - 192)) * 192 + c];
    } else {
      w = Wx[(size_t)(d*38 + 22 + (e - 208)) * 192 + c];
    }
    Wcomb[i] = f2b(w);
  }
  if (i < 4*224){
    int d = i / 224, e = i % 224;
    bcomb[i] = (e < 192) ? bdt[d*192 + e] : 0.f;
  }
  if (i < 4*384){
    int d = i / 384;
    const float* wr = &Win[(size_t)i * 96];
    const float* lb = &ln_b[d * 96];
    float s = 0.f;
    for (int c = 0; c < 96; ++c) s += wr[c] * lb[c];
    b2[i] = s;
  }
}

// ---------------- input projection (MFMA, grp-split): x-half AND z-half both scattered to seq order ----------------
__global__ __launch_bounds__(256) void kproj(const u16* __restrict__ nbf,
    const u16* __restrict__ WinMF, const float* __restrict__ b2,
    const int* __restrict__ invg, u16* __restrict__ xzs, u16* __restrict__ sz){
  int d = blockIdx.y;
  int grp = blockIdx.z;
  int wv = threadIdx.x >> 6, lane = threadIdx.x & 63;
  int lr = lane & 15, lg = lane >> 4;
  int r0 = blockIdx.x * 64 + wv * 16;           // token tile
  int row = r0 + lr;                            // 0..9215 (b*2304 + p)
  int b = row / 2304, p = row % 2304;
  const u16* Ap = nbf + (size_t)row * 96 + lg * 8;
  bf16x8 tk0 = *(const bf16x8*)(Ap);
  bf16x8 tk1 = *(const bf16x8*)(Ap + 32);
  bf16x8 tk2 = *(const bf16x8*)(Ap + 64);
  const u16* Wb = WinMF + (size_t)d * 36864 + (size_t)lr * 96 + lg * 8;
  const float* b2d = b2 + d * 384;
  int lseq = invg[d * LSEQ + p];
  size_t sbase = ((size_t)(d*4 + b) * LSEQ + lseq) * 192;
  u16* outx = xzs + sbase;
  u16* outz = sz + sbase;
  f32x4 acc[8];
  #pragma unroll
  for (int t = 0; t < 8; ++t)
    acc[t] = *(const f32x4*)&b2d[(grp*8 + t)*16 + lg*4];
  #pragma unroll
  for (int t = 0; t < 8; ++t){
    const u16* wp = Wb + (size_t)(grp*8 + t) * 1536;
    acc[t] = __builtin_amdgcn_mfma_f32_16x16x32_bf16(*(const bf16x8*)(wp     ), tk0, acc[t], 0, 0, 0);
    acc[t] = __builtin_amdgcn_mfma_f32_16x16x32_bf16(*(const bf16x8*)(wp + 32), tk1, acc[t], 0, 0, 0);
    acc[t] = __builtin_amdgcn_mfma_f32_16x16x32_bf16(*(const bf16x8*)(wp + 64), tk2, acc[t], 0, 0, 0);
  }
  #pragma unroll
  for (int t = 0; t < 8; ++t){
    int te = grp*8 + t;
    if (te < 12){
      uint2 o = pack4(acc[t][0], acc[t][1], acc[t][2], acc[t][3]);
      *(uint2*)&outx[te*16 + lg*4] = o;
    } else {
      float z0 = acc[t][0], z1 = acc[t][1], z2 = acc[t][2], z3 = acc[t][3];
      z0 *= sigmoidf_(z0); z1 *= sigmoidf_(z1); z2 *= sigmoidf_(z2); z3 *= sigmoidf_(z3);
      *(uint2*)&outz[(te-12)*16 + lg*4] = pack4(z0, z1, z2, z3);
    }
  }
}

// ---------------- FUSED (256 threads, 32-token tile, ONE barrier): conv from global -> u -> MFMA ----------------
// conv taps loaded directly from seq-ordered global (L2 absorbs 4x re-read); LDS holds only the u tile.
__global__ __launch_bounds__(256) void kconvBM(const u16* __restrict__ xzs,
    const float* __restrict__ conv_w, const float* __restrict__ conv_b,
    const u16* __restrict__ Wcomb, const float* __restrict__ bcomb,
    u16* __restrict__ u, u16* __restrict__ dtb, float* __restrict__ Bm, float* __restrict__ Cm){
  __shared__ u16 ush[32*200];
  int d = blockIdx.z, b = blockIdx.y, l0 = blockIdx.x * 32;
  int tid = threadIdx.x;
  const u16* xzd = xzs + (size_t)(d*4 + b) * LSEQ * 192;
  size_t obase = ((size_t)(d*4 + b) * LSEQ + l0) * 192;
  // conv phase: direct global taps -> SiLU -> LDS + global u  (1536 items / 256 threads = 6 each)
  #pragma unroll
  for (int it = 0; it < 6; ++it){
    int i = tid + it*256;
    int lt = i / 48, j = (i % 48) * 4;
    uint2 xv[4];
    #pragma unroll
    for (int kk = 0; kk < 4; ++kk){
      int gl = l0 + lt - 3 + kk;
      xv[kk] = (gl >= 0) ? *(const uint2*)(xzd + (size_t)gl * 192 + j) : make_uint2(0u, 0u);
    }
    float a0 = conv_b[d*192 + j + 0];
    float a1 = conv_b[d*192 + j + 1];
    float a2 = conv_b[d*192 + j + 2];
    float a3 = conv_b[d*192 + j + 3];
    const float4 w0 = *(const float4*)&conv_w[(size_t)(d*192 + j + 0) * 4];
    const float4 w1 = *(const float4*)&conv_w[(size_t)(d*192 + j + 1) * 4];
    const float4 w2 = *(const float4*)&conv_w[(size_t)(d*192 + j + 2) * 4];
    const float4 w3 = *(const float4*)&conv_w[(size_t)(d*192 + j + 3) * 4];
    const float* w0p = (const float*)&w0;
    const float* w1p = (const float*)&w1;
    const float* w2p = (const float*)&w2;
    const float* w3p = (const float*)&w3;
    #pragma unroll
    for (int kk = 0; kk < 4; ++kk){
      a0 += w0p[kk] * b2f((u16)(xv[kk].x & 0xffff));
      a1 += w1p[kk] * b2f((u16)(xv[kk].x >> 16));
      a2 += w2p[kk] * b2f((u16)(xv[kk].y & 0xffff));
      a3 += w3p[kk] * b2f((u16)(xv[kk].y >> 16));
    }
    a0 *= sigmoidf_(a0); a1 *= sigmoidf_(a1); a2 *= sigmoidf_(a2); a3 *= sigmoidf_(a3);
    uint2 r = pack4(a0, a1, a2, a3);
    *(uint2*)&ush[lt*200 + j] = r;
    *(uint2*)(u + obase + (size_t)lt * 192 + j) = r;
  }
  __syncthreads();
  // MFMA phase: 4 waves = 2 row-groups x 2 tile-halves
  int wv = tid >> 6, lane = tid & 63;
  int lr = lane & 15, lg = lane >> 4;
  int rg = wv & 1, half = wv >> 1;
  const u16* urow = &ush[(rg*16 + lr)*200 + lg*8];
  bf16x8 tk[6];
  #pragma unroll
  for (int kc = 0; kc < 6; ++kc) tk[kc] = *(const bf16x8*)(urow + kc*32);
  const u16* Wb = Wcomb + (size_t)d * 224 * 192 + (size_t)(half*7*16) * 192 + (size_t)lr * 192 + lg * 8;
  bf16x8 bw[2][6];
  #pragma unroll
  for (int kc = 0; kc < 6; ++kc) bw[0][kc] = *(const bf16x8*)(Wb + kc*32);
  size_t tokrow = (size_t)(d*4 + b) * LSEQ + l0 + rg*16 + lr;
  for (int k = 0; k < 7; ++k){
    int cur = k & 1;
    if (k < 6){
      const u16* wp = Wb + (size_t)(k + 1) * 3072;
      #pragma unroll
      for (int kc = 0; kc < 6; ++kc) bw[cur^1][kc] = *(const bf16x8*)(wp + kc*32);
    }
    f32x4 a = (f32x4){0.f, 0.f, 0.f, 0.f};
    #pragma unroll
    for (int kc = 0; kc < 6; ++kc)
      a = __builtin_amdgcn_mfma_f32_16x16x32_bf16(bw[cur][kc], tk[kc], a, 0, 0, 0);
    int t = half*7 + k;
    if (t < 12){
      f32x4 bb = *(const f32x4*)&bcomb[d*224 + t*16 + lg*4];
      float s0 = softplus_(a[0] + bb[0]);
      float s1 = softplus_(a[1] + bb[1]);
      float s2 = softplus_(a[2] + bb[2]);
      float s3 = softplus_(a[3] + bb[3]);
      uint2 o;
      o.x = (u32)f2h(s0) | ((u32)f2h(s1) << 16);
      o.y = (u32)f2h(s2) | ((u32)f2h(s3) << 16);
      *(uint2*)&dtb[tokrow * 192 + t*16 + lg*4] = o;
    } else if (t == 12){
      *(float4*)&Bm[tokrow * 16 + lg*4] = make_float4(a[0], a[1], a[2], a[3]);
    } else {
      *(float4*)&Cm[tokrow * 16 + lg*4] = make_float4(a[0], a[1], a[2], a[3]);
    }
  }
}

// ---------------- scan pass 1 (only serial pass, LDS-staged dt/u): y_local(+u*Dp), cumsum(dt), h_final ----------------
__global__ __launch_bounds__(192) void kernC1(const u16* __restrict__ dtb, const u16* __restrict__ u,
    const float* __restrict__ Bm, const float* __restrict__ Cm,
    const float* __restrict__ Aneg2, const float* __restrict__ Dp, const int* __restrict__ flag,
    u16* __restrict__ hfin, float* __restrict__ Send, u32* __restrict__ yS){
  __shared__ float Bsh[LC*16];
  __shared__ float Csh[LC*16];
  __shared__ u16 dtsh[LC*192];
  __shared__ u16 ush2[LC*192];
  int ch = blockIdx.x, b = blockIdx.y, d = blockIdx.z;
  int seq = d*4 + b;
  int di = threadIdx.x;
  size_t tb = (size_t)seq * LSEQ + ch * LC;
  const float* bp = Bm + tb * 16;
  const float* cp = Cm + tb * 16;
  for (int i = di; i < LC*16; i += 192){ Bsh[i] = bp[i]; Csh[i] = cp[i]; }
  {
    const uint4* dt4 = (const uint4*)(dtb + tb * 192);
    const uint4* u4  = (const uint4*)(u   + tb * 192);
    #pragma unroll
    for (int i = di; i < LC*24; i += 192){
      *(uint4*)&dtsh[i*8] = dt4[i];
      *(uint4*)&ush2[i*8] = u4[i];
    }
  }
  u32* ySp = yS + tb * 192;
  float Dpv = Dp[d*192 + di];
  float h[16];
  #pragma unroll
  for (int s = 0; s < 16; ++s) h[s] = 0.f;
  float Sacc = 0.f;
  __syncthreads();
  if (*flag == 0){
    float A2_0 = Aneg2[(d*192 + di) * 16];
    for (int j = 0; j < LC; ++j){
      float dtv = h2f(dtsh[j*192 + di]);
      float uv  = b2f(ush2[j*192 + di]);
      float Bs[16], Cs[16];
      {
        const float4* b4 = (const float4*)&Bsh[j * 16];
        const float4* c4 = (const float4*)&Csh[j * 16];
        #pragma unroll
        for (int q = 0; q < 4; ++q){
          float4 v = b4[q]; Bs[q*4]=v.x; Bs[q*4+1]=v.y; Bs[q*4+2]=v.z; Bs[q*4+3]=v.w;
          float4 w = c4[q]; Cs[q*4]=w.x; Cs[q*4+1]=w.y; Cs[q*4+2]=w.z; Cs[q*4+3]=w.w;
        }
      }
      float dtu = dtv * uv;
      float e1 = __builtin_amdgcn_exp2f(dtv * A2_0);
      float e2 = e1*e1, e4 = e2*e2, e8 = e4*e4;
      float p[8];
      p[0]=e1; p[1]=e2; p[2]=e1*e2; p[3]=e4; p[4]=e1*e4; p[5]=e2*e4; p[6]=p[2]*e4; p[7]=e8;
      float yv = uv * Dpv;
      #pragma unroll
      for (int s = 0; s < 8; ++s){
        h[s] = p[s]*h[s] + dtu*Bs[s];
        yv += h[s]*Cs[s];
        float q = p[s]*e8;
        h[s+8] = q*h[s+8] + dtu*Bs[s+8];
        yv += h[s+8]*Cs[s+8];
      }
      Sacc += dtv;
      ySp[j*192 + di] = (u32)f2h(yv) | ((u32)f2h(Sacc) << 16);
    }
  } else {
    float A2[16];
    {
      const float4* ap = (const float4*)&Aneg2[(d*192 + di) * 16];
      #pragma unroll
      for (int q = 0; q < 4; ++q){ float4 a4 = ap[q]; A2[q*4]=a4.x; A2[q*4+1]=a4.y; A2[q*4+2]=a4.z; A2[q*4+3]=a4.w; }
    }
    for (int j = 0; j < LC; ++j){
      float dtv = h2f(dtsh[j*192 + di]);
      float uv  = b2f(ush2[j*192 + di]);
      float Bs[16], Cs[16];
      {
        const float4* b4 = (const float4*)&Bsh[j * 16];
        const float4* c4 = (const float4*)&Csh[j * 16];
        #pragma unroll
        for (int q = 0; q < 4; ++q){
          float4 v = b4[q]; Bs[q*4]=v.x; Bs[q*4+1]=v.y; Bs[q*4+2]=v.z; Bs[q*4+3]=v.w;
          float4 w = c4[q]; Cs[q*4]=w.x; Cs[q*4+1]=w.y; Cs[q*4+2]=w.z; Cs[q*4+3]=w.w;
        }
      }
      float dtu = dtv * uv;
      float yv = uv * Dpv;
      #pragma unroll
      for (int s = 0; s < 16; ++s){
        h[s] = __builtin_amdgcn_exp2f(dtv * A2[s]) * h[s] + dtu * Bs[s];
        yv += h[s] * Cs[s];
      }
      Sacc += dtv;
      ySp[j*192 + di] = (u32)f2h(yv) | ((u32)f2h(Sacc) << 16);
    }
  }
  u16* hf = &hfin[((size_t)seq * NCH + ch) * 3072 + di * 16];
  uint4 o0, o1;
  o0.x = (u32)f2b(h[0])  | ((u32)f2b(h[1])  << 16);
  o0.y = (u32)f2b(h[2])  | ((u32)f2b(h[3])  << 16);
  o0.z = (u32)f2b(h[4])  | ((u32)f2b(h[5])  << 16);
  o0.w = (u32)f2b(h[6])  | ((u32)f2b(h[7])  << 16);
  o1.x = (u32)f2b(h[8])  | ((u32)f2b(h[9])  << 16);
  o1.y = (u32)f2b(h[10]) | ((u32)f2b(h[11]) << 16);
  o1.z = (u32)f2b(h[12]) | ((u32)f2b(h[13]) << 16);
  o1.w = (u32)f2b(h[14]) | ((u32)f2b(h[15]) << 16);
  *(uint4*)hf = o0;
  *(uint4*)(hf + 8) = o1;
  Send[((size_t)seq * NCH + ch) * 192 + di] = Sacc;
}

// ---------------- scan combine: parallel over (seq, di, s), batched loads ----------------
__global__ __launch_bounds__(256) void kernC2(const u16* __restrict__ hfin, const float* __restrict__ Send,
    const float* __restrict__ Aneg2, u16* __restrict__ hin){
  int t = blockIdx.x * 256 + threadIdx.x;   // t < 16*3072
  int seq = t / 3072, q = t % 3072;
  int di = q >> 4, s = q & 15;
  int d = seq >> 2;
  float A2 = Aneg2[(d*192 + di)*16 + s];
  float hr = 0.f;
  const u16* hf = hfin + (size_t)seq * NCH * 3072 + q;
  u16* hi = hin + (size_t)seq * NCH * 3072 + q;
  const float* Se = Send + (size_t)seq * NCH * 192 + di;
  for (int ch = 0; ch < NCH; ch += 8){
    float Se8[8]; u16 hf8[8];
    #pragma unroll
    for (int k = 0; k < 8; ++k){
      Se8[k] = Se[(size_t)(ch+k) * 192];
      hf8[k] = hf[(size_t)(ch+k) * 3072];
    }
    #pragma unroll
    for (int k = 0; k < 8; ++k){
      hi[(size_t)(ch+k) * 3072] = f2b(hr);
      hr = b2f(hf8[k]) + __builtin_amdgcn_exp2f(A2 * Se8[k]) * hr;
    }
  }
}

// ---------------- parallel correction + gate + output projection (MFMA) + scatter ----------------
__global__ __launch_bounds__(384) void kscan2out(const u32* __restrict__ yS,
    const float* __restrict__ Cm,
    const float* __restrict__ Aneg2, const int* __restrict__ flag, const u16* __restrict__ hin,
    const u16* __restrict__ sz,
    const u16* __restrict__ WoutMF, const int* __restrict__ g,
    u16* __restrict__ feat){
  __shared__ float Csh[64*16];
  __shared__ u16 vsh[64][200];
  int b = blockIdx.y, d = blockIdx.z;
  int seq = d*4 + b;
  int l0 = blockIdx.x * 64;
  int tid = threadIdx.x;
  int gc = tid / 192, di = tid % 192;
  int ch = blockIdx.x * 2 + gc;
  {
    const float* cp = Cm + ((size_t)seq * LSEQ + l0) * 16;
    for (int i = tid; i < 64*16; i += 384) Csh[i] = cp[i];
  }
  float hs[16];
  {
    const uint4* hi4 = (const uint4*)&hin[((size_t)seq * NCH + ch) * 3072 + di * 16];
    uint4 v0 = hi4[0], v1 = hi4[1];
    hs[0]=b2f((u16)(v0.x&0xffff)); hs[1]=b2f((u16)(v0.x>>16));
    hs[2]=b2f((u16)(v0.y&0xffff)); hs[3]=b2f((u16)(v0.y>>16));
    hs[4]=b2f((u16)(v0.z&0xffff)); hs[5]=b2f((u16)(v0.z>>16));
    hs[6]=b2f((u16)(v0.w&0xffff)); hs[7]=b2f((u16)(v0.w>>16));
    hs[8]=b2f((u16)(v1.x&0xffff)); hs[9]=b2f((u16)(v1.x>>16));
    hs[10]=b2f((u16)(v1.y&0xffff)); hs[11]=b2f((u16)(v1.y>>16));
    hs[12]=b2f((u16)(v1.z&0xffff)); hs[13]=b2f((u16)(v1.z>>16));
    hs[14]=b2f((u16)(v1.w&0xffff)); hs[15]=b2f((u16)(v1.w>>16));
  }
  size_t tb = (size_t)seq * LSEQ + ch * LC;
  const u32* ySp = yS + tb * 192;
  const u16* szp = sz  + tb * 192;
  __syncthreads();
  if (*flag == 0){
    float A2_0 = Aneg2[(d*192 + di) * 16];
    #pragma unroll
    for (int jb = 0; jb < 4; ++jb){
      u32 ys8[8]; u16 zz8[8];
      #pragma unroll
      for (int k = 0; k < 8; ++k){
        int j = jb*8 + k;
        ys8[k] = ySp[j*192 + di];
        zz8[k] = szp[j*192 + di];
      }
      #pragma unroll
      for (int k = 0; k < 8; ++k){
        int j = jb*8 + k;
        float yv = h2f((u16)(ys8[k] & 0xffff));
        float Sc = h2f((u16)(ys8[k] >> 16));
        float Cs[16];
        {
          const float4* c4 = (const float4*)&Csh[(gc*32 + j) * 16];
          #pragma unroll
          for (int q = 0; q < 4; ++q){ float4 w = c4[q]; Cs[q*4]=w.x; Cs[q*4+1]=w.y; Cs[q*4+2]=w.z; Cs[q*4+3]=w.w; }
        }
        float e1 = __builtin_amdgcn_exp2f(Sc * A2_0);
        float e2 = e1*e1, e4 = e2*e2, e8 = e4*e4;
        float p[8];
        p[0]=e1; p[1]=e2; p[2]=e1*e2; p[3]=e4; p[4]=e1*e4; p[5]=e2*e4; p[6]=p[2]*e4; p[7]=e8;
        float corr = 0.f;
        #pragma unroll
        for (int s = 0; s < 8; ++s){
          corr += p[s]    * hs[s]   * Cs[s];
          corr += p[s]*e8 * hs[s+8] * Cs[s+8];
        }
        float szv = b2f(zz8[k]);
        vsh[gc*32 + j][di] = f2b((yv + corr) * szv);
      }
    }
  } else {
    float A2[16];
    {
      const float4* ap = (const float4*)&Aneg2[(d*192 + di) * 16];
      #pragma unroll
      for (int q = 0; q < 4; ++q){ float4 a4 = ap[q]; A2[q*4]=a4.x; A2[q*4+1]=a4.y; A2[q*4+2]=a4.z; A2[q*4+3]=a4.w; }
    }
    #pragma unroll
    for (int jb = 0; jb < 4; ++jb){
      u32 ys8[8]; u16 zz8[8];
      #pragma unroll
      for (int k = 0; k < 8; ++k){
        int j = jb*8 + k;
        ys8[k] = ySp[j*192 + di];
        zz8[k] = szp[j*192 + di];
      }
      #pragma unroll
      for (int k = 0; k < 8; ++k){
        int j = jb*8 + k;
        float yv = h2f((u16)(ys8[k] & 0xffff));
        float Sc = h2f((u16)(ys8[k] >> 16));
        float Cs[16];
        {
          const float4* c4 = (const float4*)&Csh[(gc*32 + j) * 16];
          #pragma unroll
          for (int q = 0; q < 4; ++q){ float4 w = c4[q]; Cs[q*4]=w.x; Cs[q*4+1]=w.y; Cs[q*4+2]=w.z; Cs[q*4+3]=w.w; }
        }
        float corr = 0.f;
        #pragma unroll
        for (int s = 0; s < 16; ++s)
          corr += __builtin_amdgcn_exp2f(Sc * A2[s]) * hs[s] * Cs[s];
        float szv = b2f(zz8[k]);
        vsh[gc*32 + j][di] = f2b((yv + corr) * szv);
      }
    }
  }
  __syncthreads();
  if (tid < 256){
    int wv = tid >> 6, lane = tid & 63;
    int lr = lane & 15, lg = lane >> 4;
    bf16x8 tk[6];
    #pragma unroll
    for (int kc = 0; kc < 6; ++kc)
      tk[kc] = *(const bf16x8*)&vsh[wv*16 + lr][kc*32 + lg*8];
    const u16* Wb = WoutMF + (size_t)d * 18432 + (size_t)lr * 192 + lg * 8;
    f32x4 acc[6];
    #pragma unroll
    for (int t = 0; t < 6; ++t) acc[t] = (f32x4){0.f, 0.f, 0.f, 0.f};
    #pragma unroll
    for (int t = 0; t < 6; ++t){
      const u16* wp = Wb + (size_t)t * 3072;
      #pragma unroll
      for (int kc = 0; kc < 6; ++kc)
        acc[t] = __builtin_amdgcn_mfma_f32_16x16x32_bf16(*(const bf16x8*)(wp + kc*32), tk[kc], acc[t], 0, 0, 0);
    }
    u16* fd = feat + (size_t)seq * LSEQ * 96;
    int p = g[d*LSEQ + l0 + wv*16 + lr];
    #pragma unroll
    for (int t = 0; t < 6; ++t){
      uint2 o = pack4(acc[t][0], acc[t][1], acc[t][2], acc[t][3]);
      *(uint2*)&fd[(size_t)p * 96 + t*16 + lg*4] = o;
    }
  }
}

// ---------------- combine branches: out = x * sigmoid(sum/4) ----------------
__global__ __launch_bounds__(256) void kernE(const float* __restrict__ x, const u16* __restrict__ feat,
    float* __restrict__ out){
  __shared__ float acc[64 * 97];
  int p0 = blockIdx.x * 64, b = blockIdx.y;
  int tid = threadIdx.x;
  const size_t DS_ = (size_t)4 * LSEQ * 96;
  size_t base = ((size_t)b * LSEQ + p0) * 96;
  for (int i = tid; i < 3072; i += 256){
    int pp = i / 48, c2 = (i % 48) * 2;
    size_t o = base + (size_t)pp * 96 + c2;
    u32 v0 = *(const u32*)(feat + o);
    u32 v1 = *(const u32*)(feat + DS_ + o);
    u32 v2 = *(const u32*)(feat + 2*DS_ + o);
    u32 v3 = *(const u32*)(feat + 3*DS_ + o);
    float s0 = b2f((u16)(v0 & 0xffff)) + b2f((u16)(v1 & 0xffff)) + b2f((u16)(v2 & 0xffff)) + b2f((u16)(v3 & 0xffff));
    float s1 = b2f((u16)(v0 >> 16)) + b2f((u16)(v1 >> 16)) + b2f((u16)(v2 >> 16)) + b2f((u16)(v3 >> 16));
    acc[pp*97 + c2] = s0;
    acc[pp*97 + c2 + 1] = s1;
  }
  __syncthreads();
  for (int i = tid; i < 6144; i += 256){
    int c = i / 64, pp = i % 64;
    size_t o = ((size_t)b * 96 + c) * LSEQ + p0 + pp;
    out[o] = x[o] * sigmoidf_(acc[pp*97 + c] * 0.25f);
  }
}

extern "C" void kernel_launch(void* const* d_in, const int* in_sizes, int n_in,
                              void* d_out, int out_size, void* d_ws, size_t ws_size,
                              hipStream_t stream) {
  const float* x      = (const float*)d_in[0];
  const float* ln_g   = (const float*)d_in[1];
  const float* ln_b   = (const float*)d_in[2];
  const float* Win    = (const float*)d_in[3];
  const float* conv_w = (const float*)d_in[4];
  const float* conv_b = (const float*)d_in[5];
  const float* Wx     = (const float*)d_in[6];
  const float* Wdt    = (const float*)d_in[7];
  const float* bdt    = (const float*)d_in[8];
  const float* A_log  = (const float*)d_in[9];
  const float* Dp     = (const float*)d_in[10];
  const float* Wout   = (const float*)d_in[11];

  char* W = (char*)d_ws;
  char* W0 = W;
  auto alloc = [&](size_t bytes) -> char* {
    char* p = W; W += (bytes + 255) & ~(size_t)255; return p;
  };
  int*   g      = (int*)  alloc((size_t)4 * LSEQ * 4);
  int*   invg   = (int*)  alloc((size_t)4 * LSEQ * 4);
  int*   flag   = (int*)  alloc(256);
  float* Aneg2  = (float*)alloc((size_t)4 * 192 * 16 * 4);
  float* b2     = (float*)alloc((size_t)4 * 384 * 4);
  u16*   WinMF  = (u16*)  alloc((size_t)4 * 384 * 96 * 2);
  u16*   WoutMF = (u16*)  alloc((size_t)4 * 96 * 192 * 2);
  u16*   Wcomb  = (u16*)  alloc((size_t)4 * 224 * 192 * 2);
  float* bcomb  = (float*)alloc((size_t)4 * 224 * 4);
  u16*   nbf    = (u16*)  alloc((size_t)9216 * 96 * 2);
  u16*   xzs    = (u16*)  alloc((size_t)16 * LSEQ * 192 * 2);
  u16*   ubf    = (u16*)  alloc((size_t)16 * LSEQ * 192 * 2);
  u16*   szbf   = (u16*)  alloc((size_t)16 * LSEQ * 192 * 2);
  u16*   dtb    = (u16*)  alloc((size_t)16 * LSEQ * 192 * 2);
  float* Bm     = (float*)alloc((size_t)16 * LSEQ * 16 * 4);
  float* Cm     = (float*)alloc((size_t)16 * LSEQ * 16 * 4);
  u32*   ySbuf  = (u32*)  alloc((size_t)16 * LSEQ * 192 * 4);
  float* Send   = (float*)alloc((size_t)16 * NCH * 192 * 4);
  u16*   hfin   = (u16*)  alloc((size_t)16 * NCH * 3072 * 2);
  u16*   hin    = (u16*)  alloc((size_t)16 * NCH * 3072 * 2);
  u16*   feat   = (u16*)  alloc((size_t)16 * LSEQ * 96 * 2);
  if ((size_t)(W - W0) > ws_size) return;

  hipMemsetAsync(flag, 0, sizeof(int), stream);
  prep_fold<<<912, 256, 0, stream>>>(Win, ln_g, ln_b, A_log, Wout, Wx, Wdt, bdt, x,
                                     WinMF, b2, Aneg2, WoutMF, Wcomb, bcomb, g, invg, flag, nbf);
  kproj<<<dim3(144, 4, 3), 256, 0, stream>>>(nbf, WinMF, b2, invg, xzs, szbf);
  kconvBM<<<dim3(72, 4, 4), 256, 0, stream>>>(xzs, conv_w, conv_b, Wcomb, bcomb,
                                              ubf, dtb, Bm, Cm);
  kernC1<<<dim3(NCH, 4, 4), 192, 0, stream>>>(dtb, ubf, Bm, Cm, Aneg2, Dp, flag, hfin, Send, ySbuf);
  kernC2<<<192, 256, 0, stream>>>(hfin, Send, Aneg2, hin);
  kscan2out<<<dim3(36, 4, 4), 384, 0, stream>>>(ySbuf, Cm, Aneg2, flag, hin, szbf,
                                                WoutMF, g, feat);
  kernE<<<dim3(36, 4), 256, 0, stream>>>(x, feat, (float*)d_out);
}

// Round 20
// 169.010 us; speedup vs baseline: 1.0065x; 1.0065x over previous
//
#include <hip/hip_runtime.h>
#include <math.h>

#define LSEQ 2304
#define LC 32
#define NCH 72

typedef unsigned short u16;
typedef unsigned int u32;
typedef __attribute__((ext_vector_type(8))) short bf16x8;
typedef __attribute__((ext_vector_type(4))) float f32x4;

__device__ __forceinline__ float sigmoidf_(float v){ return 1.f/(1.f+__expf(-v)); }
__device__ __forceinline__ u16 f2b(float f){
  union{float f; u32 u;} v; v.f = f;
  u32 r = v.u + 0x7fffu + ((v.u >> 16) & 1u);
  return (u16)(r >> 16);
}
__device__ __forceinline__ float b2f(u16 h){
  union{u32 u; float f;} v; v.u = ((u32)h) << 16; return v.f;
}
__device__ __forceinline__ u16 f2h(float f){
  _Float16 h = (_Float16)f;
  union{_Float16 h; u16 u;} v; v.h = h; return v.u;
}
__device__ __forceinline__ float h2f(u16 u){
  union{u16 u; _Float16 h;} v; v.u = u; return (float)v.h;
}
__device__ __forceinline__ uint2 pack4(float a, float b, float c, float d){
  uint2 o;
  o.x = (u32)f2b(a) | ((u32)f2b(b) << 16);
  o.y = (u32)f2b(c) | ((u32)f2b(d) << 16);
  return o;
}
__device__ __forceinline__ float softplus_(float v){
  return fmaxf(v, 0.f) + __logf(1.f + __expf(-fabsf(v)));
}

// ---------------- prep (g + invg + LayerNorm merged): fold LN into Win, Wcomb, A2, Wout bf16, A-check ----------------
__global__ __launch_bounds__(256) void prep_fold(const float* __restrict__ Win, const float* __restrict__ ln_g,
                          const float* __restrict__ ln_b, const float* __restrict__ A_log,
                          const float* __restrict__ Wout, const float* __restrict__ Wx,
                          const float* __restrict__ Wdt, const float* __restrict__ bdt,
                          const float* __restrict__ x,
                          u16* __restrict__ WinMF, float* __restrict__ b2,
                          float* __restrict__ Aneg2, u16* __restrict__ WoutMF,
                          u16* __restrict__ Wcomb, float* __restrict__ bcomb,
                          int* __restrict__ g, int* __restrict__ invg, int* __restrict__ flag,
                          u16* __restrict__ n){
  __shared__ float red[512];
  if (blockIdx.x >= 768){
    int tid = threadIdx.x;
    int s = tid & 63, q = tid >> 6;
    int T = (blockIdx.x - 768) * 64 + s;
    int b = T / 2304, p = T % 2304;
    const float* xp = x + (size_t)b * 96 * 2304 + p;
    float vals[24];
    float sum = 0.f, ss = 0.f;
    #pragma unroll
    for (int k = 0; k < 24; ++k){
      float v = xp[(size_t)(q*24 + k) * 2304];
      vals[k] = v; sum += v; ss += v*v;
    }
    red[q*64 + s] = sum;
    red[256 + q*64 + s] = ss;
    __syncthreads();
    float S = red[s] + red[64+s] + red[128+s] + red[192+s];
    float Q = red[256+s] + red[320+s] + red[384+s] + red[448+s];
    float mu = S * (1.f/96.f);
    float var = Q * (1.f/96.f) - mu*mu;
    float rs = rsqrtf(var + 1e-5f);
    u32 w[12];
    #pragma unroll
    for (int k = 0; k < 12; ++k){
      float v0 = (vals[2*k]   - mu) * rs;
      float v1 = (vals[2*k+1] - mu) * rs;
      w[k] = (u32)f2b(v0) | ((u32)f2b(v1) << 16);
    }
    uint4* np_ = (uint4*)(n + (size_t)T * 96 + q*24);
    np_[0] = make_uint4(w[0], w[1], w[2],  w[3]);
    np_[1] = make_uint4(w[4], w[5], w[6],  w[7]);
    np_[2] = make_uint4(w[8], w[9], w[10], w[11]);
    return;
  }
  int i = blockIdx.x * 256 + threadIdx.x;
  if (i < LSEQ){
    int l = i;
    g[l] = l;                                   // row
    g[LSEQ + l] = (l % 48) * 48 + l / 48;       // col
    invg[l] = l;
    invg[LSEQ + l] = (l % 48) * 48 + l / 48;    // col is self-inverse
    int p = i;                                  // diag (scatter) + anti (flip of diag)
    int ii = p / 48, jj = p % 48, dd = jj - ii;
    int off = (dd <= 0) ? (47 + dd) * (48 + dd) / 2
                        : 1176 + 48 * (dd - 1) - dd * (dd - 1) / 2;
    int l2 = off + min(ii, jj);
    g[2 * LSEQ + l2] = p;
    g[3 * LSEQ + l2] = ii * 48 + 47 - jj;
    invg[2 * LSEQ + p] = l2;
    invg[3 * LSEQ + ii * 48 + 47 - jj] = l2;
  }
  if (i < 4*192*16){
    float a = -expf(A_log[i]);
    Aneg2[i] = a * 1.44269504f;   // -exp(A_log)*log2(e)
    int s = i & 15;
    float a0 = -expf(A_log[i - s]);
    if (fabsf(a - (float)(s + 1) * a0) > 1e-5f * fabsf(a) + 1e-30f)
      atomicOr(flag, 1);
  }
  if (i < 4*384*96){
    int d = i / 36864, r = i % 36864, c = r % 96;
    WinMF[i] = f2b(Win[i] * ln_g[d*96 + c]);
  }
  if (i < 4*96*192) WoutMF[i] = f2b(Wout[i]);
  if (i < 4*224*192){
    int d = i / 43008, r = i % 43008, e = r / 192, c = r % 192;
    float w;
    if (e < 192){
      const float* wdt = &Wdt[(size_t)(d*192 + e) * 6];
      w = 0.f;
      #pragma unroll
      for (int r6 = 0; r6 < 6; ++r6) w += wdt[r6] * Wx[(size_t)(d*38 + r6) * 192 + c];
    } else if (e < 208){
      w = Wx[(size_t)(d*38 + 6 + (e - 192)) * 192 + c];
    } else {
      w = Wx[(size_t)(d*38 + 22 + (e - 208)) * 192 + c];
    }
    Wcomb[i] = f2b(w);
  }
  if (i < 4*224){
    int d = i / 224, e = i % 224;
    bcomb[i] = (e < 192) ? bdt[d*192 + e] : 0.f;
  }
  if (i < 4*384){
    int d = i / 384;
    const float* wr = &Win[(size_t)i * 96];
    const float* lb = &ln_b[d * 96];
    float s = 0.f;
    for (int c = 0; c < 96; ++c) s += wr[c] * lb[c];
    b2[i] = s;
  }
}

// ---------------- input projection (MFMA, grp-split): x-half AND z-half both scattered to seq order ----------------
__global__ __launch_bounds__(256) void kproj(const u16* __restrict__ nbf,
    const u16* __restrict__ WinMF, const float* __restrict__ b2,
    const int* __restrict__ invg, u16* __restrict__ xzs, u16* __restrict__ sz){
  int d = blockIdx.y;
  int grp = blockIdx.z;
  int wv = threadIdx.x >> 6, lane = threadIdx.x & 63;
  int lr = lane & 15, lg = lane >> 4;
  int r0 = blockIdx.x * 64 + wv * 16;           // token tile
  int row = r0 + lr;                            // 0..9215 (b*2304 + p)
  int b = row / 2304, p = row % 2304;
  const u16* Ap = nbf + (size_t)row * 96 + lg * 8;
  bf16x8 tk0 = *(const bf16x8*)(Ap);
  bf16x8 tk1 = *(const bf16x8*)(Ap + 32);
  bf16x8 tk2 = *(const bf16x8*)(Ap + 64);
  const u16* Wb = WinMF + (size_t)d * 36864 + (size_t)lr * 96 + lg * 8;
  const float* b2d = b2 + d * 384;
  int lseq = invg[d * LSEQ + p];
  size_t sbase = ((size_t)(d*4 + b) * LSEQ + lseq) * 192;
  u16* outx = xzs + sbase;
  u16* outz = sz + sbase;
  f32x4 acc[8];
  #pragma unroll
  for (int t = 0; t < 8; ++t)
    acc[t] = *(const f32x4*)&b2d[(grp*8 + t)*16 + lg*4];
  #pragma unroll
  for (int t = 0; t < 8; ++t){
    const u16* wp = Wb + (size_t)(grp*8 + t) * 1536;
    acc[t] = __builtin_amdgcn_mfma_f32_16x16x32_bf16(*(const bf16x8*)(wp     ), tk0, acc[t], 0, 0, 0);
    acc[t] = __builtin_amdgcn_mfma_f32_16x16x32_bf16(*(const bf16x8*)(wp + 32), tk1, acc[t], 0, 0, 0);
    acc[t] = __builtin_amdgcn_mfma_f32_16x16x32_bf16(*(const bf16x8*)(wp + 64), tk2, acc[t], 0, 0, 0);
  }
  #pragma unroll
  for (int t = 0; t < 8; ++t){
    int te = grp*8 + t;
    if (te < 12){
      uint2 o = pack4(acc[t][0], acc[t][1], acc[t][2], acc[t][3]);
      *(uint2*)&outx[te*16 + lg*4] = o;
    } else {
      float z0 = acc[t][0], z1 = acc[t][1], z2 = acc[t][2], z3 = acc[t][3];
      z0 *= sigmoidf_(z0); z1 *= sigmoidf_(z1); z2 *= sigmoidf_(z2); z3 *= sigmoidf_(z3);
      *(uint2*)&outz[(te-12)*16 + lg*4] = pack4(z0, z1, z2, z3);
    }
  }
}

// ---------------- FUSED (256 threads, 32-token tile): batched-load conv -> u -> MFMA ----------------
// All 24 tap loads issued up-front into registers; conv weights staged once in LDS.
__global__ __launch_bounds__(256) void kconvBM(const u16* __restrict__ xzs,
    const float* __restrict__ conv_w, const float* __restrict__ conv_b,
    const u16* __restrict__ Wcomb, const float* __restrict__ bcomb,
    u16* __restrict__ u, u16* __restrict__ dtb, float* __restrict__ Bm, float* __restrict__ Cm){
  __shared__ u16 ush[32*200];
  __shared__ float cwsh[192*4];
  __shared__ float cbsh[192];
  int d = blockIdx.z, b = blockIdx.y, l0 = blockIdx.x * 32;
  int tid = threadIdx.x;
  const u16* xzd = xzs + (size_t)(d*4 + b) * LSEQ * 192;
  size_t obase = ((size_t)(d*4 + b) * LSEQ + l0) * 192;
  // stage conv weights to LDS (once per block)
  for (int i = tid; i < 192; i += 256){
    cbsh[i] = conv_b[d*192 + i];
    *(float4*)&cwsh[i*4] = *(const float4*)&conv_w[(size_t)(d*192 + i) * 4];
  }
  // batched tap loads: all 24 in flight before any compute
  uint2 xv[6][4];
  #pragma unroll
  for (int it = 0; it < 6; ++it){
    int i = tid + it*256;
    int lt = i / 48, j = (i % 48) * 4;
    #pragma unroll
    for (int kk = 0; kk < 4; ++kk){
      int gl = l0 + lt - 3 + kk;
      xv[it][kk] = (gl >= 0) ? *(const uint2*)(xzd + (size_t)gl * 192 + j) : make_uint2(0u, 0u);
    }
  }
  __syncthreads();   // weights staged
  #pragma unroll
  for (int it = 0; it < 6; ++it){
    int i = tid + it*256;
    int lt = i / 48, j = (i % 48) * 4;
    float a0 = cbsh[j + 0];
    float a1 = cbsh[j + 1];
    float a2 = cbsh[j + 2];
    float a3 = cbsh[j + 3];
    #pragma unroll
    for (int kk = 0; kk < 4; ++kk){
      a0 += cwsh[(j+0)*4 + kk] * b2f((u16)(xv[it][kk].x & 0xffff));
      a1 += cwsh[(j+1)*4 + kk] * b2f((u16)(xv[it][kk].x >> 16));
      a2 += cwsh[(j+2)*4 + kk] * b2f((u16)(xv[it][kk].y & 0xffff));
      a3 += cwsh[(j+3)*4 + kk] * b2f((u16)(xv[it][kk].y >> 16));
    }
    a0 *= sigmoidf_(a0); a1 *= sigmoidf_(a1); a2 *= sigmoidf_(a2); a3 *= sigmoidf_(a3);
    uint2 r = pack4(a0, a1, a2, a3);
    *(uint2*)&ush[lt*200 + j] = r;
    *(uint2*)(u + obase + (size_t)lt * 192 + j) = r;
  }
  __syncthreads();
  // MFMA phase: 4 waves = 2 row-groups x 2 tile-halves
  int wv = tid >> 6, lane = tid & 63;
  int lr = lane & 15, lg = lane >> 4;
  int rg = wv & 1, half = wv >> 1;
  const u16* urow = &ush[(rg*16 + lr)*200 + lg*8];
  bf16x8 tk[6];
  #pragma unroll
  for (int kc = 0; kc < 6; ++kc) tk[kc] = *(const bf16x8*)(urow + kc*32);
  const u16* Wb = Wcomb + (size_t)d * 224 * 192 + (size_t)(half*7*16) * 192 + (size_t)lr * 192 + lg * 8;
  bf16x8 bw[2][6];
  #pragma unroll
  for (int kc = 0; kc < 6; ++kc) bw[0][kc] = *(const bf16x8*)(Wb + kc*32);
  size_t tokrow = (size_t)(d*4 + b) * LSEQ + l0 + rg*16 + lr;
  for (int k = 0; k < 7; ++k){
    int cur = k & 1;
    if (k < 6){
      const u16* wp = Wb + (size_t)(k + 1) * 3072;
      #pragma unroll
      for (int kc = 0; kc < 6; ++kc) bw[cur^1][kc] = *(const bf16x8*)(wp + kc*32);
    }
    f32x4 a = (f32x4){0.f, 0.f, 0.f, 0.f};
    #pragma unroll
    for (int kc = 0; kc < 6; ++kc)
      a = __builtin_amdgcn_mfma_f32_16x16x32_bf16(bw[cur][kc], tk[kc], a, 0, 0, 0);
    int t = half*7 + k;
    if (t < 12){
      f32x4 bb = *(const f32x4*)&bcomb[d*224 + t*16 + lg*4];
      float s0 = softplus_(a[0] + bb[0]);
      float s1 = softplus_(a[1] + bb[1]);
      float s2 = softplus_(a[2] + bb[2]);
      float s3 = softplus_(a[3] + bb[3]);
      uint2 o;
      o.x = (u32)f2h(s0) | ((u32)f2h(s1) << 16);
      o.y = (u32)f2h(s2) | ((u32)f2h(s3) << 16);
      *(uint2*)&dtb[tokrow * 192 + t*16 + lg*4] = o;
    } else if (t == 12){
      *(float4*)&Bm[tokrow * 16 + lg*4] = make_float4(a[0], a[1], a[2], a[3]);
    } else {
      *(float4*)&Cm[tokrow * 16 + lg*4] = make_float4(a[0], a[1], a[2], a[3]);
    }
  }
}

// ---------------- scan pass 1 (only serial pass, LDS-staged dt/u): y_local(+u*Dp), cumsum(dt), h_final ----------------
__global__ __launch_bounds__(192) void kernC1(const u16* __restrict__ dtb, const u16* __restrict__ u,
    const float* __restrict__ Bm, const float* __restrict__ Cm,
    const float* __restrict__ Aneg2, const float* __restrict__ Dp, const int* __restrict__ flag,
    u16* __restrict__ hfin, float* __restrict__ Send, u32* __restrict__ yS){
  __shared__ float Bsh[LC*16];
  __shared__ float Csh[LC*16];
  __shared__ u16 dtsh[LC*192];
  __shared__ u16 ush2[LC*192];
  int ch = blockIdx.x, b = blockIdx.y, d = blockIdx.z;
  int seq = d*4 + b;
  int di = threadIdx.x;
  size_t tb = (size_t)seq * LSEQ + ch * LC;
  const float* bp = Bm + tb * 16;
  const float* cp = Cm + tb * 16;
  for (int i = di; i < LC*16; i += 192){ Bsh[i] = bp[i]; Csh[i] = cp[i]; }
  {
    const uint4* dt4 = (const uint4*)(dtb + tb * 192);
    const uint4* u4  = (const uint4*)(u   + tb * 192);
    #pragma unroll
    for (int i = di; i < LC*24; i += 192){
      *(uint4*)&dtsh[i*8] = dt4[i];
      *(uint4*)&ush2[i*8] = u4[i];
    }
  }
  u32* ySp = yS + tb * 192;
  float Dpv = Dp[d*192 + di];
  float h[16];
  #pragma unroll
  for (int s = 0; s < 16; ++s) h[s] = 0.f;
  float Sacc = 0.f;
  __syncthreads();
  if (*flag == 0){
    float A2_0 = Aneg2[(d*192 + di) * 16];
    for (int j = 0; j < LC; ++j){
      float dtv = h2f(dtsh[j*192 + di]);
      float uv  = b2f(ush2[j*192 + di]);
      float Bs[16], Cs[16];
      {
        const float4* b4 = (const float4*)&Bsh[j * 16];
        const float4* c4 = (const float4*)&Csh[j * 16];
        #pragma unroll
        for (int q = 0; q < 4; ++q){
          float4 v = b4[q]; Bs[q*4]=v.x; Bs[q*4+1]=v.y; Bs[q*4+2]=v.z; Bs[q*4+3]=v.w;
          float4 w = c4[q]; Cs[q*4]=w.x; Cs[q*4+1]=w.y; Cs[q*4+2]=w.z; Cs[q*4+3]=w.w;
        }
      }
      float dtu = dtv * uv;
      float e1 = __builtin_amdgcn_exp2f(dtv * A2_0);
      float e2 = e1*e1, e4 = e2*e2, e8 = e4*e4;
      float p[8];
      p[0]=e1; p[1]=e2; p[2]=e1*e2; p[3]=e4; p[4]=e1*e4; p[5]=e2*e4; p[6]=p[2]*e4; p[7]=e8;
      float yv = uv * Dpv;
      #pragma unroll
      for (int s = 0; s < 8; ++s){
        h[s] = p[s]*h[s] + dtu*Bs[s];
        yv += h[s]*Cs[s];
        float q = p[s]*e8;
        h[s+8] = q*h[s+8] + dtu*Bs[s+8];
        yv += h[s+8]*Cs[s+8];
      }
      Sacc += dtv;
      ySp[j*192 + di] = (u32)f2h(yv) | ((u32)f2h(Sacc) << 16);
    }
  } else {
    float A2[16];
    {
      const float4* ap = (const float4*)&Aneg2[(d*192 + di) * 16];
      #pragma unroll
      for (int q = 0; q < 4; ++q){ float4 a4 = ap[q]; A2[q*4]=a4.x; A2[q*4+1]=a4.y; A2[q*4+2]=a4.z; A2[q*4+3]=a4.w; }
    }
    for (int j = 0; j < LC; ++j){
      float dtv = h2f(dtsh[j*192 + di]);
      float uv  = b2f(ush2[j*192 + di]);
      float Bs[16], Cs[16];
      {
        const float4* b4 = (const float4*)&Bsh[j * 16];
        const float4* c4 = (const float4*)&Csh[j * 16];
        #pragma unroll
        for (int q = 0; q < 4; ++q){
          float4 v = b4[q]; Bs[q*4]=v.x; Bs[q*4+1]=v.y; Bs[q*4+2]=v.z; Bs[q*4+3]=v.w;
          float4 w = c4[q]; Cs[q*4]=w.x; Cs[q*4+1]=w.y; Cs[q*4+2]=w.z; Cs[q*4+3]=w.w;
        }
      }
      float dtu = dtv * uv;
      float yv = uv * Dpv;
      #pragma unroll
      for (int s = 0; s < 16; ++s){
        h[s] = __builtin_amdgcn_exp2f(dtv * A2[s]) * h[s] + dtu * Bs[s];
        yv += h[s] * Cs[s];
      }
      Sacc += dtv;
      ySp[j*192 + di] = (u32)f2h(yv) | ((u32)f2h(Sacc) << 16);
    }
  }
  u16* hf = &hfin[((size_t)seq * NCH + ch) * 3072 + di * 16];
  uint4 o0, o1;
  o0.x = (u32)f2b(h[0])  | ((u32)f2b(h[1])  << 16);
  o0.y = (u32)f2b(h[2])  | ((u32)f2b(h[3])  << 16);
  o0.z = (u32)f2b(h[4])  | ((u32)f2b(h[5])  << 16);
  o0.w = (u32)f2b(h[6])  | ((u32)f2b(h[7])  << 16);
  o1.x = (u32)f2b(h[8])  | ((u32)f2b(h[9])  << 16);
  o1.y = (u32)f2b(h[10]) | ((u32)f2b(h[11]) << 16);
  o1.z = (u32)f2b(h[12]) | ((u32)f2b(h[13]) << 16);
  o1.w = (u32)f2b(h[14]) | ((u32)f2b(h[15]) << 16);
  *(uint4*)hf = o0;
  *(uint4*)(hf + 8) = o1;
  Send[((size_t)seq * NCH + ch) * 192 + di] = Sacc;
}

// ---------------- scan combine: parallel over (seq, di, s), batched loads ----------------
__global__ __launch_bounds__(256) void kernC2(const u16* __restrict__ hfin, const float* __restrict__ Send,
    const float* __restrict__ Aneg2, u16* __restrict__ hin){
  int t = blockIdx.x * 256 + threadIdx.x;   // t < 16*3072
  int seq = t / 3072, q = t % 3072;
  int di = q >> 4, s = q & 15;
  int d = seq >> 2;
  float A2 = Aneg2[(d*192 + di)*16 + s];
  float hr = 0.f;
  const u16* hf = hfin + (size_t)seq * NCH * 3072 + q;
  u16* hi = hin + (size_t)seq * NCH * 3072 + q;
  const float* Se = Send + (size_t)seq * NCH * 192 + di;
  for (int ch = 0; ch < NCH; ch += 8){
    float Se8[8]; u16 hf8[8];
    #pragma unroll
    for (int k = 0; k < 8; ++k){
      Se8[k] = Se[(size_t)(ch+k) * 192];
      hf8[k] = hf[(size_t)(ch+k) * 3072];
    }
    #pragma unroll
    for (int k = 0; k < 8; ++k){
      hi[(size_t)(ch+k) * 3072] = f2b(hr);
      hr = b2f(hf8[k]) + __builtin_amdgcn_exp2f(A2 * Se8[k]) * hr;
    }
  }
}

// ---------------- parallel correction + gate + output projection (MFMA) + scatter ----------------
__global__ __launch_bounds__(384) void kscan2out(const u32* __restrict__ yS,
    const float* __restrict__ Cm,
    const float* __restrict__ Aneg2, const int* __restrict__ flag, const u16* __restrict__ hin,
    const u16* __restrict__ sz,
    const u16* __restrict__ WoutMF, const int* __restrict__ g,
    u16* __restrict__ feat){
  __shared__ float Csh[64*16];
  __shared__ u16 vsh[64][200];
  int b = blockIdx.y, d = blockIdx.z;
  int seq = d*4 + b;
  int l0 = blockIdx.x * 64;
  int tid = threadIdx.x;
  int gc = tid / 192, di = tid % 192;
  int ch = blockIdx.x * 2 + gc;
  {
    const float* cp = Cm + ((size_t)seq * LSEQ + l0) * 16;
    for (int i = tid; i < 64*16; i += 384) Csh[i] = cp[i];
  }
  float hs[16];
  {
    const uint4* hi4 = (const uint4*)&hin[((size_t)seq * NCH + ch) * 3072 + di * 16];
    uint4 v0 = hi4[0], v1 = hi4[1];
    hs[0]=b2f((u16)(v0.x&0xffff)); hs[1]=b2f((u16)(v0.x>>16));
    hs[2]=b2f((u16)(v0.y&0xffff)); hs[3]=b2f((u16)(v0.y>>16));
    hs[4]=b2f((u16)(v0.z&0xffff)); hs[5]=b2f((u16)(v0.z>>16));
    hs[6]=b2f((u16)(v0.w&0xffff)); hs[7]=b2f((u16)(v0.w>>16));
    hs[8]=b2f((u16)(v1.x&0xffff)); hs[9]=b2f((u16)(v1.x>>16));
    hs[10]=b2f((u16)(v1.y&0xffff)); hs[11]=b2f((u16)(v1.y>>16));
    hs[12]=b2f((u16)(v1.z&0xffff)); hs[13]=b2f((u16)(v1.z>>16));
    hs[14]=b2f((u16)(v1.w&0xffff)); hs[15]=b2f((u16)(v1.w>>16));
  }
  size_t tb = (size_t)seq * LSEQ + ch * LC;
  const u32* ySp = yS + tb * 192;
  const u16* szp = sz  + tb * 192;
  __syncthreads();
  if (*flag == 0){
    float A2_0 = Aneg2[(d*192 + di) * 16];
    #pragma unroll
    for (int jb = 0; jb < 4; ++jb){
      u32 ys8[8]; u16 zz8[8];
      #pragma unroll
      for (int k = 0; k < 8; ++k){
        int j = jb*8 + k;
        ys8[k] = ySp[j*192 + di];
        zz8[k] = szp[j*192 + di];
      }
      #pragma unroll
      for (int k = 0; k < 8; ++k){
        int j = jb*8 + k;
        float yv = h2f((u16)(ys8[k] & 0xffff));
        float Sc = h2f((u16)(ys8[k] >> 16));
        float Cs[16];
        {
          const float4* c4 = (const float4*)&Csh[(gc*32 + j) * 16];
          #pragma unroll
          for (int q = 0; q < 4; ++q){ float4 w = c4[q]; Cs[q*4]=w.x; Cs[q*4+1]=w.y; Cs[q*4+2]=w.z; Cs[q*4+3]=w.w; }
        }
        float e1 = __builtin_amdgcn_exp2f(Sc * A2_0);
        float e2 = e1*e1, e4 = e2*e2, e8 = e4*e4;
        float p[8];
        p[0]=e1; p[1]=e2; p[2]=e1*e2; p[3]=e4; p[4]=e1*e4; p[5]=e2*e4; p[6]=p[2]*e4; p[7]=e8;
        float corr = 0.f;
        #pragma unroll
        for (int s = 0; s < 8; ++s){
          corr += p[s]    * hs[s]   * Cs[s];
          corr += p[s]*e8 * hs[s+8] * Cs[s+8];
        }
        float szv = b2f(zz8[k]);
        vsh[gc*32 + j][di] = f2b((yv + corr) * szv);
      }
    }
  } else {
    float A2[16];
    {
      const float4* ap = (const float4*)&Aneg2[(d*192 + di) * 16];
      #pragma unroll
      for (int q = 0; q < 4; ++q){ float4 a4 = ap[q]; A2[q*4]=a4.x; A2[q*4+1]=a4.y; A2[q*4+2]=a4.z; A2[q*4+3]=a4.w; }
    }
    #pragma unroll
    for (int jb = 0; jb < 4; ++jb){
      u32 ys8[8]; u16 zz8[8];
      #pragma unroll
      for (int k = 0; k < 8; ++k){
        int j = jb*8 + k;
        ys8[k] = ySp[j*192 + di];
        zz8[k] = szp[j*192 + di];
      }
      #pragma unroll
      for (int k = 0; k < 8; ++k){
        int j = jb*8 + k;
        float yv = h2f((u16)(ys8[k] & 0xffff));
        float Sc = h2f((u16)(ys8[k] >> 16));
        float Cs[16];
        {
          const float4* c4 = (const float4*)&Csh[(gc*32 + j) * 16];
          #pragma unroll
          for (int q = 0; q < 4; ++q){ float4 w = c4[q]; Cs[q*4]=w.x; Cs[q*4+1]=w.y; Cs[q*4+2]=w.z; Cs[q*4+3]=w.w; }
        }
        float corr = 0.f;
        #pragma unroll
        for (int s = 0; s < 16; ++s)
          corr += __builtin_amdgcn_exp2f(Sc * A2[s]) * hs[s] * Cs[s];
        float szv = b2f(zz8[k]);
        vsh[gc*32 + j][di] = f2b((yv + corr) * szv);
      }
    }
  }
  __syncthreads();
  if (tid < 256){
    int wv = tid >> 6, lane = tid & 63;
    int lr = lane & 15, lg = lane >> 4;
    bf16x8 tk[6];
    #pragma unroll
    for (int kc = 0; kc < 6; ++kc)
      tk[kc] = *(const bf16x8*)&vsh[wv*16 + lr][kc*32 + lg*8];
    const u16* Wb = WoutMF + (size_t)d * 18432 + (size_t)lr * 192 + lg * 8;
    f32x4 acc[6];
    #pragma unroll
    for (int t = 0; t < 6; ++t) acc[t] = (f32x4){0.f, 0.f, 0.f, 0.f};
    #pragma unroll
    for (int t = 0; t < 6; ++t){
      const u16* wp = Wb + (size_t)t * 3072;
      #pragma unroll
      for (int kc = 0; kc < 6; ++kc)
        acc[t] = __builtin_amdgcn_mfma_f32_16x16x32_bf16(*(const bf16x8*)(wp + kc*32), tk[kc], acc[t], 0, 0, 0);
    }
    u16* fd = feat + (size_t)seq * LSEQ * 96;
    int p = g[d*LSEQ + l0 + wv*16 + lr];
    #pragma unroll
    for (int t = 0; t < 6; ++t){
      uint2 o = pack4(acc[t][0], acc[t][1], acc[t][2], acc[t][3]);
      *(uint2*)&fd[(size_t)p * 96 + t*16 + lg*4] = o;
    }
  }
}

// ---------------- combine branches: out = x * sigmoid(sum/4) ----------------
__global__ __launch_bounds__(256) void kernE(const float* __restrict__ x, const u16* __restrict__ feat,
    float* __restrict__ out){
  __shared__ float acc[64 * 97];
  int p0 = blockIdx.x * 64, b = blockIdx.y;
  int tid = threadIdx.x;
  const size_t DS_ = (size_t)4 * LSEQ * 96;
  size_t base = ((size_t)b * LSEQ + p0) * 96;
  for (int i = tid; i < 3072; i += 256){
    int pp = i / 48, c2 = (i % 48) * 2;
    size_t o = base + (size_t)pp * 96 + c2;
    u32 v0 = *(const u32*)(feat + o);
    u32 v1 = *(const u32*)(feat + DS_ + o);
    u32 v2 = *(const u32*)(feat + 2*DS_ + o);
    u32 v3 = *(const u32*)(feat + 3*DS_ + o);
    float s0 = b2f((u16)(v0 & 0xffff)) + b2f((u16)(v1 & 0xffff)) + b2f((u16)(v2 & 0xffff)) + b2f((u16)(v3 & 0xffff));
    float s1 = b2f((u16)(v0 >> 16)) + b2f((u16)(v1 >> 16)) + b2f((u16)(v2 >> 16)) + b2f((u16)(v3 >> 16));
    acc[pp*97 + c2] = s0;
    acc[pp*97 + c2 + 1] = s1;
  }
  __syncthreads();
  for (int i = tid; i < 6144; i += 256){
    int c = i / 64, pp = i % 64;
    size_t o = ((size_t)b * 96 + c) * LSEQ + p0 + pp;
    out[o] = x[o] * sigmoidf_(acc[pp*97 + c] * 0.25f);
  }
}

extern "C" void kernel_launch(void* const* d_in, const int* in_sizes, int n_in,
                              void* d_out, int out_size, void* d_ws, size_t ws_size,
                              hipStream_t stream) {
  const float* x      = (const float*)d_in[0];
  const float* ln_g   = (const float*)d_in[1];
  const float* ln_b   = (const float*)d_in[2];
  const float* Win    = (const float*)d_in[3];
  const float* conv_w = (const float*)d_in[4];
  const float* conv_b = (const float*)d_in[5];
  const float* Wx     = (const float*)d_in[6];
  const float* Wdt    = (const float*)d_in[7];
  const float* bdt    = (const float*)d_in[8];
  const float* A_log  = (const float*)d_in[9];
  const float* Dp     = (const float*)d_in[10];
  const float* Wout   = (const float*)d_in[11];

  char* W = (char*)d_ws;
  char* W0 = W;
  auto alloc = [&](size_t bytes) -> char* {
    char* p = W; W += (bytes + 255) & ~(size_t)255; return p;
  };
  int*   g      = (int*)  alloc((size_t)4 * LSEQ * 4);
  int*   invg   = (int*)  alloc((size_t)4 * LSEQ * 4);
  int*   flag   = (int*)  alloc(256);
  float* Aneg2  = (float*)alloc((size_t)4 * 192 * 16 * 4);
  float* b2     = (float*)alloc((size_t)4 * 384 * 4);
  u16*   WinMF  = (u16*)  alloc((size_t)4 * 384 * 96 * 2);
  u16*   WoutMF = (u16*)  alloc((size_t)4 * 96 * 192 * 2);
  u16*   Wcomb  = (u16*)  alloc((size_t)4 * 224 * 192 * 2);
  float* bcomb  = (float*)alloc((size_t)4 * 224 * 4);
  u16*   nbf    = (u16*)  alloc((size_t)9216 * 96 * 2);
  u16*   xzs    = (u16*)  alloc((size_t)16 * LSEQ * 192 * 2);
  u16*   ubf    = (u16*)  alloc((size_t)16 * LSEQ * 192 * 2);
  u16*   szbf   = (u16*)  alloc((size_t)16 * LSEQ * 192 * 2);
  u16*   dtb    = (u16*)  alloc((size_t)16 * LSEQ * 192 * 2);
  float* Bm     = (float*)alloc((size_t)16 * LSEQ * 16 * 4);
  float* Cm     = (float*)alloc((size_t)16 * LSEQ * 16 * 4);
  u32*   ySbuf  = (u32*)  alloc((size_t)16 * LSEQ * 192 * 4);
  float* Send   = (float*)alloc((size_t)16 * NCH * 192 * 4);
  u16*   hfin   = (u16*)  alloc((size_t)16 * NCH * 3072 * 2);
  u16*   hin    = (u16*)  alloc((size_t)16 * NCH * 3072 * 2);
  u16*   feat   = (u16*)  alloc((size_t)16 * LSEQ * 96 * 2);
  if ((size_t)(W - W0) > ws_size) return;

  hipMemsetAsync(flag, 0, sizeof(int), stream);
  prep_fold<<<912, 256, 0, stream>>>(Win, ln_g, ln_b, A_log, Wout, Wx, Wdt, bdt, x,
                                     WinMF, b2, Aneg2, WoutMF, Wcomb, bcomb, g, invg, flag, nbf);
  kproj<<<dim3(144, 4, 3), 256, 0, stream>>>(nbf, WinMF, b2, invg, xzs, szbf);
  kconvBM<<<dim3(72, 4, 4), 256, 0, stream>>>(xzs, conv_w, conv_b, Wcomb, bcomb,
                                              ubf, dtb, Bm, Cm);
  kernC1<<<dim3(NCH, 4, 4), 192, 0, stream>>>(dtb, ubf, Bm, Cm, Aneg2, Dp, flag, hfin, Send, ySbuf);
  kernC2<<<192, 256, 0, stream>>>(hfin, Send, Aneg2, hin);
  kscan2out<<<dim3(36, 4, 4), 384, 0, stream>>>(ySbuf, Cm, Aneg2, flag, hin, szbf,
                                                WoutMF, g, feat);
  kernE<<<dim3(36, 4), 256, 0, stream>>>(x, feat, (float*)d_out);
}